// Round 9
// baseline (523.459 us; speedup 1.0000x reference)
//
#include <hip/hip_runtime.h>
#include <hip/hip_fp16.h>

// R10 (resubmit after GPU-acquisition timeout): GEMM LDS tiles K-outer
// ([kchunk][row][8]) so ds_read_b128 fragment reads hit all 32 banks (was
// 8-of-32, 7.96M conflict cycles/dispatch = ~12% of kernel time).
// global_load_lds dest stays linear; SOURCE global address permuted per-thread
// (rule: both-sides-or-neither). nt stores: removed for fp16 out (qkvh re-read
// by attn + partial-line RMW inflated WRITE 166->202MB); kept for fp32 out.
// Pipeline (counted-vmcnt triple buffer), cpb-parallel, attn unchanged.

typedef _Float16 half8 __attribute__((ext_vector_type(8)));
typedef _Float16 half4v __attribute__((ext_vector_type(4)));
typedef float floatx4 __attribute__((ext_vector_type(4)));

#define BW 512
#define NTOK 144
#define CDIM 384
#define NH 12
#define HD 32
#define MROWS (BW * NTOK)      // 73728
#define QKVN (3 * CDIM)        // 1152

__device__ inline void llds16(const void* g, void* l) {
    __builtin_amdgcn_global_load_lds((const __attribute__((address_space(1))) void*)g,
                                     (__attribute__((address_space(3))) void*)l, 16, 0, 0);
}

__device__ inline void cstore(_Float16* p, float v) { *p = (_Float16)v; }
__device__ inline void cstore(float* p, float v) { __builtin_nontemporal_store(v, p); }

// ---------------- cast fp32 -> fp16, 8 elems/thread ----------------
__global__ __launch_bounds__(256) void cast_f2h(const float* __restrict__ s,
                                                _Float16* __restrict__ d, int n8) {
    int i = blockIdx.x * 256 + threadIdx.x;
    if (i >= n8) return;
    const float4* s4 = (const float4*)s;
    float4 a = s4[2 * i], b = s4[2 * i + 1];
    half8 h;
    h[0] = (_Float16)a.x; h[1] = (_Float16)a.y; h[2] = (_Float16)a.z; h[3] = (_Float16)a.w;
    h[4] = (_Float16)b.x; h[5] = (_Float16)b.y; h[6] = (_Float16)b.z; h[7] = (_Float16)b.w;
    ((half8*)d)[i] = h;
}

// cast both weight matrices in one launch
__global__ __launch_bounds__(256) void cast_weights(const float* __restrict__ w_qkv,
                                                    _Float16* __restrict__ qh,
                                                    const float* __restrict__ w_proj,
                                                    _Float16* __restrict__ ph) {
    const int nq = QKVN * CDIM / 8;            // 55296
    const int np = CDIM * CDIM / 8;            // 18432
    int i = blockIdx.x * 256 + threadIdx.x;
    const float4* s4; half8* d8; int j;
    if (i < nq) { s4 = (const float4*)w_qkv; d8 = (half8*)qh; j = i; }
    else if (i < nq + np) { s4 = (const float4*)w_proj; d8 = (half8*)ph; j = i - nq; }
    else return;
    float4 a = s4[2 * j], b = s4[2 * j + 1];
    half8 h;
    h[0] = (_Float16)a.x; h[1] = (_Float16)a.y; h[2] = (_Float16)a.z; h[3] = (_Float16)a.w;
    h[4] = (_Float16)b.x; h[5] = (_Float16)b.y; h[6] = (_Float16)b.z; h[7] = (_Float16)b.w;
    d8[j] = h;
}

// ---------------- CPB MLP: 529 rel positions -> 12 heads ----------------
__global__ __launch_bounds__(256) void cpb_table(const float* __restrict__ w1,
                                                 const float* __restrict__ b1,
                                                 const float* __restrict__ w2,
                                                 float* __restrict__ tab) {
    const int t = blockIdx.x;          // 0..528
    const int j = threadIdx.x;         // 0..255
    float u0 = (float)((t / 23) - 11) * (12.0f / 11.0f);
    float u1 = (float)((t % 23) - 11) * (12.0f / 11.0f);
    float x0 = copysignf(log2f(fabsf(u0) + 1.0f) * (1.0f / 3.0f), u0);
    float x1 = copysignf(log2f(fabsf(u1) + 1.0f) * (1.0f / 3.0f), u1);

    float acc[12] = {};
#pragma unroll
    for (int half = 0; half < 2; half++) {
        const int jj = j + half * 256;
        float hj = fmaf(x0, w1[2 * jj], fmaf(x1, w1[2 * jj + 1], b1[jj]));
        hj = fmaxf(hj, 0.0f);
#pragma unroll
        for (int q = 0; q < 12; q++) acc[q] += hj * w2[q * 512 + jj];
    }
#pragma unroll
    for (int q = 0; q < 12; q++) {
        acc[q] += __shfl_xor(acc[q], 1);  acc[q] += __shfl_xor(acc[q], 2);
        acc[q] += __shfl_xor(acc[q], 4);  acc[q] += __shfl_xor(acc[q], 8);
        acc[q] += __shfl_xor(acc[q], 16); acc[q] += __shfl_xor(acc[q], 32);
    }
    __shared__ float red[4][12];
    const int wv = j >> 6, l = j & 63;
    if (l == 0) {
#pragma unroll
        for (int q = 0; q < 12; q++) red[wv][q] = acc[q];
    }
    __syncthreads();
    if (j < 12) tab[t * 12 + j] = red[0][j] + red[1][j] + red[2][j] + red[3][j];
}

// ---------------- CM[m][h][i][j] = mask[m,i,j] + 16*sigmoid(bias[h,i,j]) ----------------
__global__ __launch_bounds__(256) void build_cm(const float* __restrict__ mask,
                                                const float* __restrict__ tab,
                                                float* __restrict__ CM) {
    int e = blockIdx.x * 256 + threadIdx.x;
    if (e >= 4 * NH * NTOK * NTOK) return;
    int j = e % NTOK; int r1 = e / NTOK;
    int i = r1 % NTOK; int r2 = r1 / NTOK;
    int h = r2 % NH;   int m = r2 / NH;
    int rt = ((i / 12) - (j / 12) + 11) * 23 + ((i % 12) - (j % 12) + 11);
    float bv = tab[rt * 12 + h];
    CM[e] = mask[m * (NTOK * NTOK) + i * NTOK + j] + 16.0f / (1.0f + __expf(-bv));
}

// ---------------- GEMM: C[m,n] = A[m,:]·B[n,:] + bias[n]; A (M,K), B (N,K) fp16 ----------------
// 256x128 tile, 512 threads / 8 waves (each wave 64x64). 1D grid, XCD-swizzled.
// Counted-vmcnt triple-buffer pipeline: vmcnt(3) + one raw s_barrier per K-step.
// LDS K-outer layout: As = [4 kchunks][256 rows][8 fp16], Bs = [4][128][8].
//   read  : &As[lk*2048 + row*8]  -> 16 consecutive rows = 32 banks (conflict-free)
//   write : global_load_lds linear dest; SOURCE addr permuted per thread.
template <typename OutT>
__global__ __launch_bounds__(512) void gemm_bt(const _Float16* __restrict__ A,
                                               const _Float16* __restrict__ B,
                                               const float* __restrict__ bias,
                                               OutT* __restrict__ C, int M, int N, int K) {
    __shared__ __align__(16) _Float16 As[3][256 * 32];   // 3 x 16 KB
    __shared__ __align__(16) _Float16 Bs[3][128 * 32];   // 3 x  8 KB
    const int t = threadIdx.x;
    const int wv = t >> 6, l = t & 63;
    const int wm = wv >> 1, wn = wv & 1;              // wm 0..3 (M), wn 0..1 (N)
    const int lr = l & 15, lk = l >> 4;

    const int ntn = N >> 7;                           // N-tiles
    const int t8 = gridDim.x >> 3;                    // tiles per XCD
    const int tile = (blockIdx.x & 7) * t8 + (blockIdx.x >> 3);
    const long m0 = (long)(tile / ntn) * 256, n0 = (long)(tile % ntn) * 128;

    // K-outer staging: thread t owns LDS halfwords [t*8] (+[t*8+4096] for A hi).
    //   A lo : kc = t>>8 (0..1), row = t&255 ;  A hi: kc = 2+(t>>8) via ag+16
    //   B    : kc = t>>7 (0..3), row = t&127
    const _Float16* ag = A + (m0 + (t & 255)) * (long)K + ((t >> 8) * 8);
    const _Float16* bg = B + (n0 + (t & 127)) * (long)K + ((t >> 7) * 8);

    floatx4 acc[4][4] = {};
    const int nk = K >> 5;                            // K=384 -> 12
    const int aoff = wm * 64 + lr, boff = wn * 64 + lr;

    // prologue: stage tiles 0 and 1 (6 loads in flight)
    llds16(ag,      &As[0][t * 8]);
    llds16(ag + 16, &As[0][t * 8 + 4096]);
    llds16(bg,      &Bs[0][t * 8]);
    ag += 32; bg += 32;
    llds16(ag,      &As[1][t * 8]);
    llds16(ag + 16, &As[1][t * 8 + 4096]);
    llds16(bg,      &Bs[1][t * 8]);
    ag += 32; bg += 32;

    int cur = 0, nx2 = 2;
    for (int it = 0; it < nk - 1; ++it) {
        // oldest 3 loads (tile it) landed; tiles it+1 (,it+2) stay in flight
        asm volatile("s_waitcnt vmcnt(3)" ::: "memory");
        __builtin_amdgcn_s_barrier();
        __builtin_amdgcn_sched_barrier(0);

        if (it + 2 < nk) {   // stage tile it+2 (its readers retired pre-barrier)
            llds16(ag,      &As[nx2][t * 8]);
            llds16(ag + 16, &As[nx2][t * 8 + 4096]);
            llds16(bg,      &Bs[nx2][t * 8]);
            ag += 32; bg += 32;
        }

        half8 af[4], bf[4];
#pragma unroll
        for (int fi = 0; fi < 4; fi++)
            af[fi] = *(const half8*)&As[cur][lk * 2048 + (aoff + fi * 16) * 8];
#pragma unroll
        for (int fj = 0; fj < 4; fj++)
            bf[fj] = *(const half8*)&Bs[cur][lk * 1024 + (boff + fj * 16) * 8];
#pragma unroll
        for (int fi = 0; fi < 4; fi++)
#pragma unroll
            for (int fj = 0; fj < 4; fj++)
                acc[fi][fj] = __builtin_amdgcn_mfma_f32_16x16x32_f16(af[fi], bf[fj], acc[fi][fj], 0, 0, 0);

        cur = (cur == 2) ? 0 : cur + 1;
        nx2 = (nx2 == 2) ? 0 : nx2 + 1;
    }

    {   // final tile: drain everything
        asm volatile("s_waitcnt vmcnt(0)" ::: "memory");
        __builtin_amdgcn_s_barrier();
        __builtin_amdgcn_sched_barrier(0);
        half8 af[4], bf[4];
#pragma unroll
        for (int fi = 0; fi < 4; fi++)
            af[fi] = *(const half8*)&As[cur][lk * 2048 + (aoff + fi * 16) * 8];
#pragma unroll
        for (int fj = 0; fj < 4; fj++)
            bf[fj] = *(const half8*)&Bs[cur][lk * 1024 + (boff + fj * 16) * 8];
#pragma unroll
        for (int fi = 0; fi < 4; fi++)
#pragma unroll
            for (int fj = 0; fj < 4; fj++)
                acc[fi][fj] = __builtin_amdgcn_mfma_f32_16x16x32_f16(af[fi], bf[fj], acc[fi][fj], 0, 0, 0);
    }

#pragma unroll
    for (int fi = 0; fi < 4; fi++) {
        const long row = m0 + wm * 64 + fi * 16 + lk * 4;
#pragma unroll
        for (int fj = 0; fj < 4; fj++) {
            const long col = n0 + wn * 64 + fj * 16 + lr;
            const float bv = bias[col];
#pragma unroll
            for (int r = 0; r < 4; r++) {
                float v = acc[fi][fj][r] + bv;
                cstore(&C[(row + r) * (long)N + col], v);
            }
        }
    }
}

// ---------------- windowed attention: one block per (window, head), 9 waves ----------------
// S^T formulation: s[cj] = mfma(K_frag, Q_frag) -> lane holds S^T[token=cj*16+lk*4+r][q=wv*16+lr].
// Softmax is 36 in-lane values + shfl_xor(16/32). The exp'ed fragment is directly the
// B-operand of the 16x16x16 PV MFMA (P never goes to LDS). O^T comes out in registers.
__global__ __launch_bounds__(576) void attn_win(const _Float16* __restrict__ qkv,
                                                const float* __restrict__ CM,
                                                const float* __restrict__ lscale,
                                                _Float16* __restrict__ O) {
    __shared__ __align__(16) _Float16 Kn[NTOK * HD];        // 9216 B
    __shared__ __align__(16) _Float16 Vt[HD * NTOK];        // 9216 B (transposed: [d][token])

    const int bid = blockIdx.x;
    const int w = bid / NH, h = bid % NH;
    const int t = threadIdx.x;
    const int wv = t >> 6, l = t & 63;
    const int lr = l & 15, lk = l >> 4;

    const float sc = expf(fminf(lscale[h], 4.6051701859880914f));  // exp(min(ls, log(100)))

    // ---- stage K (normalized) and V (transposed) ----
    {
        const int row = t >> 2, part = t & 3;
        const size_t base = (size_t)(w * NTOK + row) * QKVN + h * HD + part * 8;
        half8 kv = *(const half8*)(qkv + base + CDIM);
        float ss = 0.f;
#pragma unroll
        for (int j = 0; j < 8; j++) { float f = (float)kv[j]; ss += f * f; }
        ss += __shfl_xor(ss, 1); ss += __shfl_xor(ss, 2);
        float inv = 1.0f / fmaxf(sqrtf(ss), 1e-12f);
        half8 kn;
#pragma unroll
        for (int j = 0; j < 8; j++) kn[j] = (_Float16)((float)kv[j] * inv);
        *(half8*)&Kn[row * HD + part * 8] = kn;

        half8 vv = *(const half8*)(qkv + base + 2 * CDIM);
#pragma unroll
        for (int j = 0; j < 8; j++) Vt[(part * 8 + j) * NTOK + row] = vv[j];
    }

    // ---- Q fragment for this wave's 16 rows: load global, normalize, fold in scale ----
    half8 aq;
    {
        const size_t qb = (size_t)(w * NTOK + wv * 16 + lr) * QKVN + h * HD + lk * 8;
        half8 q = *(const half8*)(qkv + qb);
        float ss = 0.f;
#pragma unroll
        for (int j = 0; j < 8; j++) { float f = (float)q[j]; ss += f * f; }
        ss += __shfl_xor(ss, 16); ss += __shfl_xor(ss, 32);
        float inv = sc / fmaxf(sqrtf(ss), 1e-12f);
#pragma unroll
        for (int j = 0; j < 8; j++) aq[j] = (_Float16)((float)q[j] * inv);
    }
    __syncthreads();

    // ---- S^T = Kn Qn^T (144 tokens x 16 q-rows per wave), + CM ----
    floatx4 s[9];
#pragma unroll
    for (int cj = 0; cj < 9; cj++) {
        half8 bk = *(const half8*)&Kn[(cj * 16 + lr) * HD + lk * 8];
        floatx4 z = {};
        s[cj] = __builtin_amdgcn_mfma_f32_16x16x32_f16(bk, aq, z, 0, 0, 0);
    }
    // CM[i=q][j=token]: lane reads 4 consecutive j -> coalesced float4
    const float* cmb = CM + (size_t)((w & 3) * NH + h) * (NTOK * NTOK)
                     + (size_t)(wv * 16 + lr) * NTOK + lk * 4;
#pragma unroll
    for (int cj = 0; cj < 9; cj++) {
        float4 c4 = *(const float4*)(cmb + cj * 16);
        s[cj][0] += c4.x; s[cj][1] += c4.y; s[cj][2] += c4.z; s[cj][3] += c4.w;
    }

    // ---- softmax over token axis: 36 in-lane + cross-lk shuffles ----
    float m = s[0][0];
#pragma unroll
    for (int cj = 0; cj < 9; cj++)
#pragma unroll
        for (int r = 0; r < 4; r++) m = fmaxf(m, s[cj][r]);
    m = fmaxf(m, __shfl_xor(m, 16)); m = fmaxf(m, __shfl_xor(m, 32));
    float sum = 0.f;
#pragma unroll
    for (int cj = 0; cj < 9; cj++)
#pragma unroll
        for (int r = 0; r < 4; r++) { s[cj][r] = __expf(s[cj][r] - m); sum += s[cj][r]; }
    sum += __shfl_xor(sum, 16); sum += __shfl_xor(sum, 32);
    const float inv = 1.0f / sum;

    // ---- P fragments in registers: directly the B-operand of 16x16x16 MFMA ----
    half4v pa[9];
#pragma unroll
    for (int cj = 0; cj < 9; cj++) {
        pa[cj][0] = (_Float16)s[cj][0]; pa[cj][1] = (_Float16)s[cj][1];
        pa[cj][2] = (_Float16)s[cj][2]; pa[cj][3] = (_Float16)s[cj][3];
    }

    // ---- PV: O^T[d][q] via 16x16x16 MFMA, A = V^T from Vt (contiguous half4) ----
    floatx4 o0 = {}, o1 = {};
#pragma unroll
    for (int cj = 0; cj < 9; cj++) {
        half4v v0 = *(const half4v*)&Vt[lr * NTOK + cj * 16 + lk * 4];
        half4v v1 = *(const half4v*)&Vt[(16 + lr) * NTOK + cj * 16 + lk * 4];
        o0 = __builtin_amdgcn_mfma_f32_16x16x16f16(v0, pa[cj], o0, 0, 0, 0);
        o1 = __builtin_amdgcn_mfma_f32_16x16x16f16(v1, pa[cj], o1, 0, 0, 0);
    }

    // ---- store: lane holds O^T[d=lk*4+r (+16)][q=lr] -> two contiguous half4 ----
    const size_t ob = (size_t)(w * NTOK + wv * 16 + lr) * CDIM + h * HD + lk * 4;
    half4v r0, r1;
#pragma unroll
    for (int r = 0; r < 4; r++) {
        r0[r] = (_Float16)(o0[r] * inv);
        r1[r] = (_Float16)(o1[r] * inv);
    }
    *(half4v*)&O[ob] = r0;
    *(half4v*)&O[ob + 16] = r1;
}

extern "C" void kernel_launch(void* const* d_in, const int* in_sizes, int n_in,
                              void* d_out, int out_size, void* d_ws, size_t ws_size,
                              hipStream_t stream) {
    const float* x     = (const float*)d_in[0];
    const float* mask  = (const float*)d_in[1];
    const float* qkv_w = (const float*)d_in[2];
    const float* qkv_b = (const float*)d_in[3];
    const float* lsc   = (const float*)d_in[4];
    const float* cw1   = (const float*)d_in[5];
    const float* cb1   = (const float*)d_in[6];
    const float* cw2   = (const float*)d_in[7];
    const float* pw    = (const float*)d_in[8];
    const float* pb    = (const float*)d_in[9];
    (void)in_sizes; (void)n_in; (void)out_size; (void)ws_size;

    char* ws = (char*)d_ws;
    float*    tab  = (float*)(ws);                    //    25,392 B
    float*    CM   = (float*)(ws + 25600);            // 3,981,312 B
    _Float16* qw_h = (_Float16*)(ws + 4006912);       //   884,736 B
    _Float16* pw_h = (_Float16*)(ws + 4891648);       //   294,912 B
    _Float16* x_h  = (_Float16*)(ws + 5186560);       // 56,623,104 B (reused as o_h after QKV GEMM)
    _Float16* qkvh = (_Float16*)(ws + 61809664);      // 169,869,312 B ; total ~221 MB
    _Float16* o_h  = x_h;

    cast_f2h<<<(MROWS * CDIM / 8) / 256, 256, 0, stream>>>(x, x_h, MROWS * CDIM / 8);
    cast_weights<<<(QKVN * CDIM / 8 + CDIM * CDIM / 8 + 255) / 256, 256, 0, stream>>>(
        qkv_w, qw_h, pw, pw_h);
    cpb_table<<<529, 256, 0, stream>>>(cw1, cb1, cw2, tab);
    build_cm<<<(4 * NH * NTOK * NTOK + 255) / 256, 256, 0, stream>>>(mask, tab, CM);

    gemm_bt<_Float16><<<(QKVN / 128) * (MROWS / 256), 512, 0, stream>>>(
        x_h, qw_h, qkv_b, qkvh, MROWS, QKVN, CDIM);

    attn_win<<<BW * NH, 576, 0, stream>>>(qkvh, CM, lsc, o_h);

    gemm_bt<float><<<(CDIM / 128) * (MROWS / 256), 512, 0, stream>>>(
        o_h, pw_h, pb, (float*)d_out, MROWS, CDIM, CDIM);
}

// Round 10
// 434.673 us; speedup vs baseline: 1.2043x; 1.2043x over previous
//
#include <hip/hip_runtime.h>
#include <hip/hip_fp16.h>

// R11: fix R10's coalescing regression while keeping its conflict win.
// Row-major LDS layout restored (R9 staging shape: 4 lanes cover one 64B row
// segment -> global coalescing intact). Bank conflicts killed by XOR-swizzling
// the CHUNK within each row: stage src col = ((t&3) ^ ((srow>>1)&3))*8 (same
// 64B segment, permuted), fragment read chunk = lk ^ ((lr>>1)&3).
// Read bank math: addr mod 128 = 64*(lr&1) + 16*(lk^((lr>>1)&3)) -> every bank
// exactly 2 lanes = free (m136). XOR term is per-lane constant (no loop VALU).
// Keeps: counted-vmcnt triple buffer, cpb-parallel, nt only for fp32 out.

typedef _Float16 half8 __attribute__((ext_vector_type(8)));
typedef _Float16 half4v __attribute__((ext_vector_type(4)));
typedef float floatx4 __attribute__((ext_vector_type(4)));

#define BW 512
#define NTOK 144
#define CDIM 384
#define NH 12
#define HD 32
#define MROWS (BW * NTOK)      // 73728
#define QKVN (3 * CDIM)        // 1152

__device__ inline void llds16(const void* g, void* l) {
    __builtin_amdgcn_global_load_lds((const __attribute__((address_space(1))) void*)g,
                                     (__attribute__((address_space(3))) void*)l, 16, 0, 0);
}

__device__ inline void cstore(_Float16* p, float v) { *p = (_Float16)v; }
__device__ inline void cstore(float* p, float v) { __builtin_nontemporal_store(v, p); }

// ---------------- cast fp32 -> fp16, 8 elems/thread ----------------
__global__ __launch_bounds__(256) void cast_f2h(const float* __restrict__ s,
                                                _Float16* __restrict__ d, int n8) {
    int i = blockIdx.x * 256 + threadIdx.x;
    if (i >= n8) return;
    const float4* s4 = (const float4*)s;
    float4 a = s4[2 * i], b = s4[2 * i + 1];
    half8 h;
    h[0] = (_Float16)a.x; h[1] = (_Float16)a.y; h[2] = (_Float16)a.z; h[3] = (_Float16)a.w;
    h[4] = (_Float16)b.x; h[5] = (_Float16)b.y; h[6] = (_Float16)b.z; h[7] = (_Float16)b.w;
    ((half8*)d)[i] = h;
}

// cast both weight matrices in one launch
__global__ __launch_bounds__(256) void cast_weights(const float* __restrict__ w_qkv,
                                                    _Float16* __restrict__ qh,
                                                    const float* __restrict__ w_proj,
                                                    _Float16* __restrict__ ph) {
    const int nq = QKVN * CDIM / 8;            // 55296
    const int np = CDIM * CDIM / 8;            // 18432
    int i = blockIdx.x * 256 + threadIdx.x;
    const float4* s4; half8* d8; int j;
    if (i < nq) { s4 = (const float4*)w_qkv; d8 = (half8*)qh; j = i; }
    else if (i < nq + np) { s4 = (const float4*)w_proj; d8 = (half8*)ph; j = i - nq; }
    else return;
    float4 a = s4[2 * j], b = s4[2 * j + 1];
    half8 h;
    h[0] = (_Float16)a.x; h[1] = (_Float16)a.y; h[2] = (_Float16)a.z; h[3] = (_Float16)a.w;
    h[4] = (_Float16)b.x; h[5] = (_Float16)b.y; h[6] = (_Float16)b.z; h[7] = (_Float16)b.w;
    d8[j] = h;
}

// ---------------- CPB MLP: 529 rel positions -> 12 heads ----------------
__global__ __launch_bounds__(256) void cpb_table(const float* __restrict__ w1,
                                                 const float* __restrict__ b1,
                                                 const float* __restrict__ w2,
                                                 float* __restrict__ tab) {
    const int t = blockIdx.x;          // 0..528
    const int j = threadIdx.x;         // 0..255
    float u0 = (float)((t / 23) - 11) * (12.0f / 11.0f);
    float u1 = (float)((t % 23) - 11) * (12.0f / 11.0f);
    float x0 = copysignf(log2f(fabsf(u0) + 1.0f) * (1.0f / 3.0f), u0);
    float x1 = copysignf(log2f(fabsf(u1) + 1.0f) * (1.0f / 3.0f), u1);

    float acc[12] = {};
#pragma unroll
    for (int half = 0; half < 2; half++) {
        const int jj = j + half * 256;
        float hj = fmaf(x0, w1[2 * jj], fmaf(x1, w1[2 * jj + 1], b1[jj]));
        hj = fmaxf(hj, 0.0f);
#pragma unroll
        for (int q = 0; q < 12; q++) acc[q] += hj * w2[q * 512 + jj];
    }
#pragma unroll
    for (int q = 0; q < 12; q++) {
        acc[q] += __shfl_xor(acc[q], 1);  acc[q] += __shfl_xor(acc[q], 2);
        acc[q] += __shfl_xor(acc[q], 4);  acc[q] += __shfl_xor(acc[q], 8);
        acc[q] += __shfl_xor(acc[q], 16); acc[q] += __shfl_xor(acc[q], 32);
    }
    __shared__ float red[4][12];
    const int wv = j >> 6, l = j & 63;
    if (l == 0) {
#pragma unroll
        for (int q = 0; q < 12; q++) red[wv][q] = acc[q];
    }
    __syncthreads();
    if (j < 12) tab[t * 12 + j] = red[0][j] + red[1][j] + red[2][j] + red[3][j];
}

// ---------------- CM[m][h][i][j] = mask[m,i,j] + 16*sigmoid(bias[h,i,j]) ----------------
__global__ __launch_bounds__(256) void build_cm(const float* __restrict__ mask,
                                                const float* __restrict__ tab,
                                                float* __restrict__ CM) {
    int e = blockIdx.x * 256 + threadIdx.x;
    if (e >= 4 * NH * NTOK * NTOK) return;
    int j = e % NTOK; int r1 = e / NTOK;
    int i = r1 % NTOK; int r2 = r1 / NTOK;
    int h = r2 % NH;   int m = r2 / NH;
    int rt = ((i / 12) - (j / 12) + 11) * 23 + ((i % 12) - (j % 12) + 11);
    float bv = tab[rt * 12 + h];
    CM[e] = mask[m * (NTOK * NTOK) + i * NTOK + j] + 16.0f / (1.0f + __expf(-bv));
}

// ---------------- GEMM: C[m,n] = A[m,:]·B[n,:] + bias[n]; A (M,K), B (N,K) fp16 ----------------
// 256x128 tile, 512 threads / 8 waves (each wave 64x64). 1D grid, XCD-swizzled.
// Counted-vmcnt triple-buffer pipeline: vmcnt(3) + one raw s_barrier per K-step.
// Row-major LDS + chunk XOR swizzle (coalesced staging AND conflict-free reads).
template <typename OutT>
__global__ __launch_bounds__(512) void gemm_bt(const _Float16* __restrict__ A,
                                               const _Float16* __restrict__ B,
                                               const float* __restrict__ bias,
                                               OutT* __restrict__ C, int M, int N, int K) {
    __shared__ __align__(16) _Float16 As[3][256 * 32];   // 3 x 16 KB
    __shared__ __align__(16) _Float16 Bs[3][128 * 32];   // 3 x  8 KB
    const int t = threadIdx.x;
    const int wv = t >> 6, l = t & 63;
    const int wm = wv >> 1, wn = wv & 1;              // wm 0..3 (M), wn 0..1 (N)
    const int lr = l & 15, lk = l >> 4;

    const int ntn = N >> 7;                           // N-tiles
    const int t8 = gridDim.x >> 3;                    // tiles per XCD
    const int tile = (blockIdx.x & 7) * t8 + (blockIdx.x >> 3);
    const long m0 = (long)(tile / ntn) * 256, n0 = (long)(tile % ntn) * 128;

    // staging: thread t owns LDS row srow=t>>2, chunk t&3 (linear dest t*16B).
    // source column XOR-swizzled within the row's 64B segment (coalescing kept):
    const int srow = t >> 2;
    const int scol = ((t & 3) ^ ((srow >> 1) & 3)) * 8;
    const _Float16* ag = A + (m0 + srow) * (long)K + scol;
    const _Float16* bg = B + (n0 + srow) * (long)K + scol;

    floatx4 acc[4][4] = {};
    const int nk = K >> 5;                            // K=384 -> 12
    const int aoff = wm * 64 + lr, boff = wn * 64 + lr;
    const int lka = (lk ^ ((lr >> 1) & 3)) * 8;       // swizzled read chunk (const/lane)

    // prologue: stage tiles 0 and 1 (6 loads in flight)
    llds16(ag,                  &As[0][t * 8]);
    llds16(ag + 128 * (long)K,  &As[0][t * 8 + 4096]);
    llds16(bg,                  &Bs[0][t * 8]);
    ag += 32; bg += 32;
    llds16(ag,                  &As[1][t * 8]);
    llds16(ag + 128 * (long)K,  &As[1][t * 8 + 4096]);
    llds16(bg,                  &Bs[1][t * 8]);
    ag += 32; bg += 32;

    int cur = 0, nx2 = 2;
    for (int it = 0; it < nk - 1; ++it) {
        // oldest 3 loads (tile it) landed; tiles it+1 (,it+2) stay in flight
        asm volatile("s_waitcnt vmcnt(3)" ::: "memory");
        __builtin_amdgcn_s_barrier();
        __builtin_amdgcn_sched_barrier(0);

        if (it + 2 < nk) {   // stage tile it+2 (its readers retired pre-barrier)
            llds16(ag,                 &As[nx2][t * 8]);
            llds16(ag + 128 * (long)K, &As[nx2][t * 8 + 4096]);
            llds16(bg,                 &Bs[nx2][t * 8]);
            ag += 32; bg += 32;
        }

        half8 af[4], bf[4];
#pragma unroll
        for (int fi = 0; fi < 4; fi++)
            af[fi] = *(const half8*)&As[cur][(aoff + fi * 16) * 32 + lka];
#pragma unroll
        for (int fj = 0; fj < 4; fj++)
            bf[fj] = *(const half8*)&Bs[cur][(boff + fj * 16) * 32 + lka];
#pragma unroll
        for (int fi = 0; fi < 4; fi++)
#pragma unroll
            for (int fj = 0; fj < 4; fj++)
                acc[fi][fj] = __builtin_amdgcn_mfma_f32_16x16x32_f16(af[fi], bf[fj], acc[fi][fj], 0, 0, 0);

        cur = (cur == 2) ? 0 : cur + 1;
        nx2 = (nx2 == 2) ? 0 : nx2 + 1;
    }

    {   // final tile: drain everything
        asm volatile("s_waitcnt vmcnt(0)" ::: "memory");
        __builtin_amdgcn_s_barrier();
        __builtin_amdgcn_sched_barrier(0);
        half8 af[4], bf[4];
#pragma unroll
        for (int fi = 0; fi < 4; fi++)
            af[fi] = *(const half8*)&As[cur][(aoff + fi * 16) * 32 + lka];
#pragma unroll
        for (int fj = 0; fj < 4; fj++)
            bf[fj] = *(const half8*)&Bs[cur][(boff + fj * 16) * 32 + lka];
#pragma unroll
        for (int fi = 0; fi < 4; fi++)
#pragma unroll
            for (int fj = 0; fj < 4; fj++)
                acc[fi][fj] = __builtin_amdgcn_mfma_f32_16x16x32_f16(af[fi], bf[fj], acc[fi][fj], 0, 0, 0);
    }

#pragma unroll
    for (int fi = 0; fi < 4; fi++) {
        const long row = m0 + wm * 64 + fi * 16 + lk * 4;
#pragma unroll
        for (int fj = 0; fj < 4; fj++) {
            const long col = n0 + wn * 64 + fj * 16 + lr;
            const float bv = bias[col];
#pragma unroll
            for (int r = 0; r < 4; r++) {
                float v = acc[fi][fj][r] + bv;
                cstore(&C[(row + r) * (long)N + col], v);
            }
        }
    }
}

// ---------------- windowed attention: one block per (window, head), 9 waves ----------------
// S^T formulation: s[cj] = mfma(K_frag, Q_frag) -> lane holds S^T[token=cj*16+lk*4+r][q=wv*16+lr].
// Softmax is 36 in-lane values + shfl_xor(16/32). The exp'ed fragment is directly the
// B-operand of the 16x16x16 PV MFMA (P never goes to LDS). O^T comes out in registers.
__global__ __launch_bounds__(576) void attn_win(const _Float16* __restrict__ qkv,
                                                const float* __restrict__ CM,
                                                const float* __restrict__ lscale,
                                                _Float16* __restrict__ O) {
    __shared__ __align__(16) _Float16 Kn[NTOK * HD];        // 9216 B
    __shared__ __align__(16) _Float16 Vt[HD * NTOK];        // 9216 B (transposed: [d][token])

    const int bid = blockIdx.x;
    const int w = bid / NH, h = bid % NH;
    const int t = threadIdx.x;
    const int wv = t >> 6, l = t & 63;
    const int lr = l & 15, lk = l >> 4;

    const float sc = expf(fminf(lscale[h], 4.6051701859880914f));  // exp(min(ls, log(100)))

    // ---- stage K (normalized) and V (transposed) ----
    {
        const int row = t >> 2, part = t & 3;
        const size_t base = (size_t)(w * NTOK + row) * QKVN + h * HD + part * 8;
        half8 kv = *(const half8*)(qkv + base + CDIM);
        float ss = 0.f;
#pragma unroll
        for (int j = 0; j < 8; j++) { float f = (float)kv[j]; ss += f * f; }
        ss += __shfl_xor(ss, 1); ss += __shfl_xor(ss, 2);
        float inv = 1.0f / fmaxf(sqrtf(ss), 1e-12f);
        half8 kn;
#pragma unroll
        for (int j = 0; j < 8; j++) kn[j] = (_Float16)((float)kv[j] * inv);
        *(half8*)&Kn[row * HD + part * 8] = kn;

        half8 vv = *(const half8*)(qkv + base + 2 * CDIM);
#pragma unroll
        for (int j = 0; j < 8; j++) Vt[(part * 8 + j) * NTOK + row] = vv[j];
    }

    // ---- Q fragment for this wave's 16 rows: load global, normalize, fold in scale ----
    half8 aq;
    {
        const size_t qb = (size_t)(w * NTOK + wv * 16 + lr) * QKVN + h * HD + lk * 8;
        half8 q = *(const half8*)(qkv + qb);
        float ss = 0.f;
#pragma unroll
        for (int j = 0; j < 8; j++) { float f = (float)q[j]; ss += f * f; }
        ss += __shfl_xor(ss, 16); ss += __shfl_xor(ss, 32);
        float inv = sc / fmaxf(sqrtf(ss), 1e-12f);
#pragma unroll
        for (int j = 0; j < 8; j++) aq[j] = (_Float16)((float)q[j] * inv);
    }
    __syncthreads();

    // ---- S^T = Kn Qn^T (144 tokens x 16 q-rows per wave), + CM ----
    floatx4 s[9];
#pragma unroll
    for (int cj = 0; cj < 9; cj++) {
        half8 bk = *(const half8*)&Kn[(cj * 16 + lr) * HD + lk * 8];
        floatx4 z = {};
        s[cj] = __builtin_amdgcn_mfma_f32_16x16x32_f16(bk, aq, z, 0, 0, 0);
    }
    // CM[i=q][j=token]: lane reads 4 consecutive j -> coalesced float4
    const float* cmb = CM + (size_t)((w & 3) * NH + h) * (NTOK * NTOK)
                     + (size_t)(wv * 16 + lr) * NTOK + lk * 4;
#pragma unroll
    for (int cj = 0; cj < 9; cj++) {
        float4 c4 = *(const float4*)(cmb + cj * 16);
        s[cj][0] += c4.x; s[cj][1] += c4.y; s[cj][2] += c4.z; s[cj][3] += c4.w;
    }

    // ---- softmax over token axis: 36 in-lane + cross-lk shuffles ----
    float m = s[0][0];
#pragma unroll
    for (int cj = 0; cj < 9; cj++)
#pragma unroll
        for (int r = 0; r < 4; r++) m = fmaxf(m, s[cj][r]);
    m = fmaxf(m, __shfl_xor(m, 16)); m = fmaxf(m, __shfl_xor(m, 32));
    float sum = 0.f;
#pragma unroll
    for (int cj = 0; cj < 9; cj++)
#pragma unroll
        for (int r = 0; r < 4; r++) { s[cj][r] = __expf(s[cj][r] - m); sum += s[cj][r]; }
    sum += __shfl_xor(sum, 16); sum += __shfl_xor(sum, 32);
    const float inv = 1.0f / sum;

    // ---- P fragments in registers: directly the B-operand of 16x16x16 MFMA ----
    half4v pa[9];
#pragma unroll
    for (int cj = 0; cj < 9; cj++) {
        pa[cj][0] = (_Float16)s[cj][0]; pa[cj][1] = (_Float16)s[cj][1];
        pa[cj][2] = (_Float16)s[cj][2]; pa[cj][3] = (_Float16)s[cj][3];
    }

    // ---- PV: O^T[d][q] via 16x16x16 MFMA, A = V^T from Vt (contiguous half4) ----
    floatx4 o0 = {}, o1 = {};
#pragma unroll
    for (int cj = 0; cj < 9; cj++) {
        half4v v0 = *(const half4v*)&Vt[lr * NTOK + cj * 16 + lk * 4];
        half4v v1 = *(const half4v*)&Vt[(16 + lr) * NTOK + cj * 16 + lk * 4];
        o0 = __builtin_amdgcn_mfma_f32_16x16x16f16(v0, pa[cj], o0, 0, 0, 0);
        o1 = __builtin_amdgcn_mfma_f32_16x16x16f16(v1, pa[cj], o1, 0, 0, 0);
    }

    // ---- store: lane holds O^T[d=lk*4+r (+16)][q=lr] -> two contiguous half4 ----
    const size_t ob = (size_t)(w * NTOK + wv * 16 + lr) * CDIM + h * HD + lk * 4;
    half4v r0, r1;
#pragma unroll
    for (int r = 0; r < 4; r++) {
        r0[r] = (_Float16)(o0[r] * inv);
        r1[r] = (_Float16)(o1[r] * inv);
    }
    *(half4v*)&O[ob] = r0;
    *(half4v*)&O[ob + 16] = r1;
}

extern "C" void kernel_launch(void* const* d_in, const int* in_sizes, int n_in,
                              void* d_out, int out_size, void* d_ws, size_t ws_size,
                              hipStream_t stream) {
    const float* x     = (const float*)d_in[0];
    const float* mask  = (const float*)d_in[1];
    const float* qkv_w = (const float*)d_in[2];
    const float* qkv_b = (const float*)d_in[3];
    const float* lsc   = (const float*)d_in[4];
    const float* cw1   = (const float*)d_in[5];
    const float* cb1   = (const float*)d_in[6];
    const float* cw2   = (const float*)d_in[7];
    const float* pw    = (const float*)d_in[8];
    const float* pb    = (const float*)d_in[9];
    (void)in_sizes; (void)n_in; (void)out_size; (void)ws_size;

    char* ws = (char*)d_ws;
    float*    tab  = (float*)(ws);                    //    25,392 B
    float*    CM   = (float*)(ws + 25600);            // 3,981,312 B
    _Float16* qw_h = (_Float16*)(ws + 4006912);       //   884,736 B
    _Float16* pw_h = (_Float16*)(ws + 4891648);       //   294,912 B
    _Float16* x_h  = (_Float16*)(ws + 5186560);       // 56,623,104 B (reused as o_h after QKV GEMM)
    _Float16* qkvh = (_Float16*)(ws + 61809664);      // 169,869,312 B ; total ~221 MB
    _Float16* o_h  = x_h;

    cast_f2h<<<(MROWS * CDIM / 8) / 256, 256, 0, stream>>>(x, x_h, MROWS * CDIM / 8);
    cast_weights<<<(QKVN * CDIM / 8 + CDIM * CDIM / 8 + 255) / 256, 256, 0, stream>>>(
        qkv_w, qw_h, pw, pw_h);
    cpb_table<<<529, 256, 0, stream>>>(cw1, cb1, cw2, tab);
    build_cm<<<(4 * NH * NTOK * NTOK + 255) / 256, 256, 0, stream>>>(mask, tab, CM);

    gemm_bt<_Float16><<<(QKVN / 128) * (MROWS / 256), 512, 0, stream>>>(
        x_h, qw_h, qkv_b, qkvh, MROWS, QKVN, CDIM);

    attn_win<<<BW * NH, 576, 0, stream>>>(qkvh, CM, lsc, o_h);

    gemm_bt<float><<<(CDIM / 128) * (MROWS / 256), 512, 0, stream>>>(
        o_h, pw_h, pb, (float*)d_out, MROWS, CDIM, CDIM);
}

// Round 11
// 432.558 us; speedup vs baseline: 1.2101x; 1.0049x over previous
//
#include <hip/hip_runtime.h>
#include <hip/hip_fp16.h>

// R12: (1) fuse cast_f2h + cast_weights + cpb_table into ONE prep kernel
//     (block-range dispatch; saves 2 launches + stream gaps).
//     (2) attn XCD swizzle: bid' = (bid&7)*768 + bid>>3 puts all 12 heads of
//     a window (which share qkvh rows) on the SAME XCD -> L2 hits not L3.
// GEMM (R11 chunk-XOR swizzle, counted-vmcnt triple buffer) unchanged.

typedef _Float16 half8 __attribute__((ext_vector_type(8)));
typedef _Float16 half4v __attribute__((ext_vector_type(4)));
typedef float floatx4 __attribute__((ext_vector_type(4)));

#define BW 512
#define NTOK 144
#define CDIM 384
#define NH 12
#define HD 32
#define MROWS (BW * NTOK)      // 73728
#define QKVN (3 * CDIM)        // 1152
#define NCASTB (MROWS * CDIM / 8 / 256)   // 13824 blocks casting x
#define NWB 288                           // weight-cast blocks

__device__ inline void llds16(const void* g, void* l) {
    __builtin_amdgcn_global_load_lds((const __attribute__((address_space(1))) void*)g,
                                     (__attribute__((address_space(3))) void*)l, 16, 0, 0);
}

__device__ inline void cstore(_Float16* p, float v) { *p = (_Float16)v; }
__device__ inline void cstore(float* p, float v) { __builtin_nontemporal_store(v, p); }

// ---------------- prep: cast x, cast weights, CPB-MLP table — one launch ----------------
__global__ __launch_bounds__(256) void prep(const float* __restrict__ x,
                                            _Float16* __restrict__ xh,
                                            const float* __restrict__ w_qkv,
                                            _Float16* __restrict__ qh,
                                            const float* __restrict__ w_proj,
                                            _Float16* __restrict__ ph,
                                            const float* __restrict__ w1,
                                            const float* __restrict__ b1,
                                            const float* __restrict__ w2,
                                            float* __restrict__ tab) {
    __shared__ float red[4][12];
    const int b = blockIdx.x;
    const int j = threadIdx.x;

    if (b < NCASTB) {                       // ---- cast x -> fp16, 8 elems/thread
        int i = b * 256 + j;
        const float4* s4 = (const float4*)x;
        float4 a = s4[2 * i], c = s4[2 * i + 1];
        half8 h;
        h[0] = (_Float16)a.x; h[1] = (_Float16)a.y; h[2] = (_Float16)a.z; h[3] = (_Float16)a.w;
        h[4] = (_Float16)c.x; h[5] = (_Float16)c.y; h[6] = (_Float16)c.z; h[7] = (_Float16)c.w;
        ((half8*)xh)[i] = h;
        return;
    }
    if (b < NCASTB + NWB) {                 // ---- cast both weight matrices
        const int nq = QKVN * CDIM / 8;     // 55296
        int i = (b - NCASTB) * 256 + j;
        const float4* s4; half8* d8; int k;
        if (i < nq) { s4 = (const float4*)w_qkv; d8 = (half8*)qh; k = i; }
        else        { s4 = (const float4*)w_proj; d8 = (half8*)ph; k = i - nq; }
        float4 a = s4[2 * k], c = s4[2 * k + 1];
        half8 h;
        h[0] = (_Float16)a.x; h[1] = (_Float16)a.y; h[2] = (_Float16)a.z; h[3] = (_Float16)a.w;
        h[4] = (_Float16)c.x; h[5] = (_Float16)c.y; h[6] = (_Float16)c.z; h[7] = (_Float16)c.w;
        d8[k] = h;
        return;
    }
    // ---- CPB MLP: one block per rel-position t (529 blocks)
    const int t = b - (NCASTB + NWB);       // 0..528
    float u0 = (float)((t / 23) - 11) * (12.0f / 11.0f);
    float u1 = (float)((t % 23) - 11) * (12.0f / 11.0f);
    float x0 = copysignf(log2f(fabsf(u0) + 1.0f) * (1.0f / 3.0f), u0);
    float x1 = copysignf(log2f(fabsf(u1) + 1.0f) * (1.0f / 3.0f), u1);

    float acc[12] = {};
#pragma unroll
    for (int half = 0; half < 2; half++) {
        const int jj = j + half * 256;
        float hj = fmaf(x0, w1[2 * jj], fmaf(x1, w1[2 * jj + 1], b1[jj]));
        hj = fmaxf(hj, 0.0f);
#pragma unroll
        for (int q = 0; q < 12; q++) acc[q] += hj * w2[q * 512 + jj];
    }
#pragma unroll
    for (int q = 0; q < 12; q++) {
        acc[q] += __shfl_xor(acc[q], 1);  acc[q] += __shfl_xor(acc[q], 2);
        acc[q] += __shfl_xor(acc[q], 4);  acc[q] += __shfl_xor(acc[q], 8);
        acc[q] += __shfl_xor(acc[q], 16); acc[q] += __shfl_xor(acc[q], 32);
    }
    const int wv = j >> 6, l = j & 63;
    if (l == 0) {
#pragma unroll
        for (int q = 0; q < 12; q++) red[wv][q] = acc[q];
    }
    __syncthreads();
    if (j < 12) tab[t * 12 + j] = red[0][j] + red[1][j] + red[2][j] + red[3][j];
}

// ---------------- CM[m][h][i][j] = mask[m,i,j] + 16*sigmoid(bias[h,i,j]) ----------------
__global__ __launch_bounds__(256) void build_cm(const float* __restrict__ mask,
                                                const float* __restrict__ tab,
                                                float* __restrict__ CM) {
    int e = blockIdx.x * 256 + threadIdx.x;
    if (e >= 4 * NH * NTOK * NTOK) return;
    int j = e % NTOK; int r1 = e / NTOK;
    int i = r1 % NTOK; int r2 = r1 / NTOK;
    int h = r2 % NH;   int m = r2 / NH;
    int rt = ((i / 12) - (j / 12) + 11) * 23 + ((i % 12) - (j % 12) + 11);
    float bv = tab[rt * 12 + h];
    CM[e] = mask[m * (NTOK * NTOK) + i * NTOK + j] + 16.0f / (1.0f + __expf(-bv));
}

// ---------------- GEMM: C[m,n] = A[m,:]·B[n,:] + bias[n]; A (M,K), B (N,K) fp16 ----------------
// 256x128 tile, 512 threads / 8 waves. Counted-vmcnt triple buffer, row-major
// LDS + chunk XOR swizzle (coalesced staging AND conflict-free reads).
template <typename OutT>
__global__ __launch_bounds__(512) void gemm_bt(const _Float16* __restrict__ A,
                                               const _Float16* __restrict__ B,
                                               const float* __restrict__ bias,
                                               OutT* __restrict__ C, int M, int N, int K) {
    __shared__ __align__(16) _Float16 As[3][256 * 32];   // 3 x 16 KB
    __shared__ __align__(16) _Float16 Bs[3][128 * 32];   // 3 x  8 KB
    const int t = threadIdx.x;
    const int wv = t >> 6, l = t & 63;
    const int wm = wv >> 1, wn = wv & 1;              // wm 0..3 (M), wn 0..1 (N)
    const int lr = l & 15, lk = l >> 4;

    const int ntn = N >> 7;                           // N-tiles
    const int t8 = gridDim.x >> 3;                    // tiles per XCD
    const int tile = (blockIdx.x & 7) * t8 + (blockIdx.x >> 3);
    const long m0 = (long)(tile / ntn) * 256, n0 = (long)(tile % ntn) * 128;

    const int srow = t >> 2;
    const int scol = ((t & 3) ^ ((srow >> 1) & 3)) * 8;
    const _Float16* ag = A + (m0 + srow) * (long)K + scol;
    const _Float16* bg = B + (n0 + srow) * (long)K + scol;

    floatx4 acc[4][4] = {};
    const int nk = K >> 5;                            // K=384 -> 12
    const int aoff = wm * 64 + lr, boff = wn * 64 + lr;
    const int lka = (lk ^ ((lr >> 1) & 3)) * 8;       // swizzled read chunk (const/lane)

    // prologue: stage tiles 0 and 1 (6 loads in flight)
    llds16(ag,                  &As[0][t * 8]);
    llds16(ag + 128 * (long)K,  &As[0][t * 8 + 4096]);
    llds16(bg,                  &Bs[0][t * 8]);
    ag += 32; bg += 32;
    llds16(ag,                  &As[1][t * 8]);
    llds16(ag + 128 * (long)K,  &As[1][t * 8 + 4096]);
    llds16(bg,                  &Bs[1][t * 8]);
    ag += 32; bg += 32;

    int cur = 0, nx2 = 2;
    for (int it = 0; it < nk - 1; ++it) {
        asm volatile("s_waitcnt vmcnt(3)" ::: "memory");
        __builtin_amdgcn_s_barrier();
        __builtin_amdgcn_sched_barrier(0);

        if (it + 2 < nk) {
            llds16(ag,                 &As[nx2][t * 8]);
            llds16(ag + 128 * (long)K, &As[nx2][t * 8 + 4096]);
            llds16(bg,                 &Bs[nx2][t * 8]);
            ag += 32; bg += 32;
        }

        half8 af[4], bf[4];
#pragma unroll
        for (int fi = 0; fi < 4; fi++)
            af[fi] = *(const half8*)&As[cur][(aoff + fi * 16) * 32 + lka];
#pragma unroll
        for (int fj = 0; fj < 4; fj++)
            bf[fj] = *(const half8*)&Bs[cur][(boff + fj * 16) * 32 + lka];
#pragma unroll
        for (int fi = 0; fi < 4; fi++)
#pragma unroll
            for (int fj = 0; fj < 4; fj++)
                acc[fi][fj] = __builtin_amdgcn_mfma_f32_16x16x32_f16(af[fi], bf[fj], acc[fi][fj], 0, 0, 0);

        cur = (cur == 2) ? 0 : cur + 1;
        nx2 = (nx2 == 2) ? 0 : nx2 + 1;
    }

    {   // final tile: drain everything
        asm volatile("s_waitcnt vmcnt(0)" ::: "memory");
        __builtin_amdgcn_s_barrier();
        __builtin_amdgcn_sched_barrier(0);
        half8 af[4], bf[4];
#pragma unroll
        for (int fi = 0; fi < 4; fi++)
            af[fi] = *(const half8*)&As[cur][(aoff + fi * 16) * 32 + lka];
#pragma unroll
        for (int fj = 0; fj < 4; fj++)
            bf[fj] = *(const half8*)&Bs[cur][(boff + fj * 16) * 32 + lka];
#pragma unroll
        for (int fi = 0; fi < 4; fi++)
#pragma unroll
            for (int fj = 0; fj < 4; fj++)
                acc[fi][fj] = __builtin_amdgcn_mfma_f32_16x16x32_f16(af[fi], bf[fj], acc[fi][fj], 0, 0, 0);
    }

#pragma unroll
    for (int fi = 0; fi < 4; fi++) {
        const long row = m0 + wm * 64 + fi * 16 + lk * 4;
#pragma unroll
        for (int fj = 0; fj < 4; fj++) {
            const long col = n0 + wn * 64 + fj * 16 + lr;
            const float bv = bias[col];
#pragma unroll
            for (int r = 0; r < 4; r++) {
                float v = acc[fi][fj][r] + bv;
                cstore(&C[(row + r) * (long)N + col], v);
            }
        }
    }
}

// ---------------- windowed attention: one block per (window, head), 9 waves ----------------
// S^T formulation (P in registers). XCD-swizzled blockIdx: all 12 heads of a
// window land on the same XCD (they share qkvh rows -> L2 hits, not L3).
__global__ __launch_bounds__(576) void attn_win(const _Float16* __restrict__ qkv,
                                                const float* __restrict__ CM,
                                                const float* __restrict__ lscale,
                                                _Float16* __restrict__ O) {
    __shared__ __align__(16) _Float16 Kn[NTOK * HD];        // 9216 B
    __shared__ __align__(16) _Float16 Vt[HD * NTOK];        // 9216 B (transposed: [d][token])

    const int per = gridDim.x >> 3;                          // 768
    const int bid = (blockIdx.x & 7) * per + (blockIdx.x >> 3);
    const int w = bid / NH, h = bid % NH;
    const int t = threadIdx.x;
    const int wv = t >> 6, l = t & 63;
    const int lr = l & 15, lk = l >> 4;

    const float sc = expf(fminf(lscale[h], 4.6051701859880914f));  // exp(min(ls, log(100)))

    // ---- stage K (normalized) and V (transposed) ----
    {
        const int row = t >> 2, part = t & 3;
        const size_t base = (size_t)(w * NTOK + row) * QKVN + h * HD + part * 8;
        half8 kv = *(const half8*)(qkv + base + CDIM);
        float ss = 0.f;
#pragma unroll
        for (int j = 0; j < 8; j++) { float f = (float)kv[j]; ss += f * f; }
        ss += __shfl_xor(ss, 1); ss += __shfl_xor(ss, 2);
        float inv = 1.0f / fmaxf(sqrtf(ss), 1e-12f);
        half8 kn;
#pragma unroll
        for (int j = 0; j < 8; j++) kn[j] = (_Float16)((float)kv[j] * inv);
        *(half8*)&Kn[row * HD + part * 8] = kn;

        half8 vv = *(const half8*)(qkv + base + 2 * CDIM);
#pragma unroll
        for (int j = 0; j < 8; j++) Vt[(part * 8 + j) * NTOK + row] = vv[j];
    }

    // ---- Q fragment for this wave's 16 rows: load global, normalize, fold in scale ----
    half8 aq;
    {
        const size_t qb = (size_t)(w * NTOK + wv * 16 + lr) * QKVN + h * HD + lk * 8;
        half8 q = *(const half8*)(qkv + qb);
        float ss = 0.f;
#pragma unroll
        for (int j = 0; j < 8; j++) { float f = (float)q[j]; ss += f * f; }
        ss += __shfl_xor(ss, 16); ss += __shfl_xor(ss, 32);
        float inv = sc / fmaxf(sqrtf(ss), 1e-12f);
#pragma unroll
        for (int j = 0; j < 8; j++) aq[j] = (_Float16)((float)q[j] * inv);
    }
    __syncthreads();

    // ---- S^T = Kn Qn^T (144 tokens x 16 q-rows per wave), + CM ----
    floatx4 s[9];
#pragma unroll
    for (int cj = 0; cj < 9; cj++) {
        half8 bk = *(const half8*)&Kn[(cj * 16 + lr) * HD + lk * 8];
        floatx4 z = {};
        s[cj] = __builtin_amdgcn_mfma_f32_16x16x32_f16(bk, aq, z, 0, 0, 0);
    }
    // CM[i=q][j=token]: lane reads 4 consecutive j -> coalesced float4
    const float* cmb = CM + (size_t)((w & 3) * NH + h) * (NTOK * NTOK)
                     + (size_t)(wv * 16 + lr) * NTOK + lk * 4;
#pragma unroll
    for (int cj = 0; cj < 9; cj++) {
        float4 c4 = *(const float4*)(cmb + cj * 16);
        s[cj][0] += c4.x; s[cj][1] += c4.y; s[cj][2] += c4.z; s[cj][3] += c4.w;
    }

    // ---- softmax over token axis: 36 in-lane + cross-lk shuffles ----
    float m = s[0][0];
#pragma unroll
    for (int cj = 0; cj < 9; cj++)
#pragma unroll
        for (int r = 0; r < 4; r++) m = fmaxf(m, s[cj][r]);
    m = fmaxf(m, __shfl_xor(m, 16)); m = fmaxf(m, __shfl_xor(m, 32));
    float sum = 0.f;
#pragma unroll
    for (int cj = 0; cj < 9; cj++)
#pragma unroll
        for (int r = 0; r < 4; r++) { s[cj][r] = __expf(s[cj][r] - m); sum += s[cj][r]; }
    sum += __shfl_xor(sum, 16); sum += __shfl_xor(sum, 32);
    const float inv = 1.0f / sum;

    // ---- P fragments in registers: directly the B-operand of 16x16x16 MFMA ----
    half4v pa[9];
#pragma unroll
    for (int cj = 0; cj < 9; cj++) {
        pa[cj][0] = (_Float16)s[cj][0]; pa[cj][1] = (_Float16)s[cj][1];
        pa[cj][2] = (_Float16)s[cj][2]; pa[cj][3] = (_Float16)s[cj][3];
    }

    // ---- PV: O^T[d][q] via 16x16x16 MFMA, A = V^T from Vt (contiguous half4) ----
    floatx4 o0 = {}, o1 = {};
#pragma unroll
    for (int cj = 0; cj < 9; cj++) {
        half4v v0 = *(const half4v*)&Vt[lr * NTOK + cj * 16 + lk * 4];
        half4v v1 = *(const half4v*)&Vt[(16 + lr) * NTOK + cj * 16 + lk * 4];
        o0 = __builtin_amdgcn_mfma_f32_16x16x16f16(v0, pa[cj], o0, 0, 0, 0);
        o1 = __builtin_amdgcn_mfma_f32_16x16x16f16(v1, pa[cj], o1, 0, 0, 0);
    }

    // ---- store: lane holds O^T[d=lk*4+r (+16)][q=lr] -> two contiguous half4 ----
    const size_t ob = (size_t)(w * NTOK + wv * 16 + lr) * CDIM + h * HD + lk * 4;
    half4v r0, r1;
#pragma unroll
    for (int r = 0; r < 4; r++) {
        r0[r] = (_Float16)(o0[r] * inv);
        r1[r] = (_Float16)(o1[r] * inv);
    }
    *(half4v*)&O[ob] = r0;
    *(half4v*)&O[ob + 16] = r1;
}

extern "C" void kernel_launch(void* const* d_in, const int* in_sizes, int n_in,
                              void* d_out, int out_size, void* d_ws, size_t ws_size,
                              hipStream_t stream) {
    const float* x     = (const float*)d_in[0];
    const float* mask  = (const float*)d_in[1];
    const float* qkv_w = (const float*)d_in[2];
    const float* qkv_b = (const float*)d_in[3];
    const float* lsc   = (const float*)d_in[4];
    const float* cw1   = (const float*)d_in[5];
    const float* cb1   = (const float*)d_in[6];
    const float* cw2   = (const float*)d_in[7];
    const float* pw    = (const float*)d_in[8];
    const float* pb    = (const float*)d_in[9];
    (void)in_sizes; (void)n_in; (void)out_size; (void)ws_size;

    char* ws = (char*)d_ws;
    float*    tab  = (float*)(ws);                    //    25,392 B
    float*    CM   = (float*)(ws + 25600);            // 3,981,312 B
    _Float16* qw_h = (_Float16*)(ws + 4006912);       //   884,736 B
    _Float16* pw_h = (_Float16*)(ws + 4891648);       //   294,912 B
    _Float16* x_h  = (_Float16*)(ws + 5186560);       // 56,623,104 B (reused as o_h after QKV GEMM)
    _Float16* qkvh = (_Float16*)(ws + 61809664);      // 169,869,312 B ; total ~221 MB
    _Float16* o_h  = x_h;

    prep<<<NCASTB + NWB + 529, 256, 0, stream>>>(
        x, x_h, qkv_w, qw_h, pw, pw_h, cw1, cb1, cw2, tab);
    build_cm<<<(4 * NH * NTOK * NTOK + 255) / 256, 256, 0, stream>>>(mask, tab, CM);

    gemm_bt<_Float16><<<(QKVN / 128) * (MROWS / 256), 512, 0, stream>>>(
        x_h, qw_h, qkv_b, qkvh, MROWS, QKVN, CDIM);

    attn_win<<<BW * NH, 576, 0, stream>>>(qkvh, CM, lsc, o_h);

    gemm_bt<float><<<(CDIM / 128) * (MROWS / 256), 512, 0, stream>>>(
        o_h, pw_h, pb, (float*)d_out, MROWS, CDIM, CDIM);
}